// Round 2
// baseline (1186.721 us; speedup 1.0000x reference)
//
#include <hip/hip_runtime.h>
#include <hip/hip_bf16.h>
#include <stdint.h>

typedef __hip_bfloat16 bf16;
typedef unsigned short ushort_t;

#define B_ 32
#define F_ 4096
#define S_ 8
#define D_ 512
#define H_ 2048
#define LN_EPS 1e-5f
#define EPS_ 1e-8f
#define SCALE_ 0.044194173824159216f  // 512^-0.5

__device__ __forceinline__ float b2f(ushort_t u){
  union { uint32_t i; float f; } c; c.i = ((uint32_t)u) << 16; return c.f;
}
__device__ __forceinline__ float4 ld4f(const float* p){ return *(const float4*)p; }
__device__ __forceinline__ float4 ld4h(const ushort_t* p){
  ushort4 u = *(const ushort4*)p;
  return make_float4(b2f(u.x), b2f(u.y), b2f(u.z), b2f(u.w));
}
__device__ __forceinline__ float allsum64(float v){
  #pragma unroll
  for (int o = 1; o < 64; o <<= 1) v += __shfl_xor(v, o, 64);
  return v;
}
__device__ __forceinline__ float blockSum256(float v, float* sh){
  v = allsum64(v);
  int wid = threadIdx.x >> 6, lane = threadIdx.x & 63;
  __syncthreads();
  if (lane == 0) sh[wid] = v;
  __syncthreads();
  return sh[0] + sh[1] + sh[2] + sh[3];
}
__device__ __forceinline__ float dynld(const void* p, int i, bool f32){
  return f32 ? ((const float*)p)[i] : b2f(((const ushort_t*)p)[i]);
}

// flag=1 -> tensors are fp32; flag=0 -> bf16 (heuristic on bit patterns).
__global__ void detect_dtype(const uint32_t* __restrict__ w, int* __restrict__ flag){
  __shared__ int sh;
  if (threadIdx.x == 0) sh = 0;
  __syncthreads();
  int c = 0;
  for (int i = threadIdx.x; i < 4096; i += 256){
    uint32_t e = (w[i] >> 7) & 0xFF;
    if (e == 0 || e >= 0xBF) c++;
  }
  atomicAdd(&sh, c);
  __syncthreads();
  if (threadIdx.x == 0) *flag = (sh >= 100) ? 1 : 0;
}

// C = A @ B(^T).  A_CMB: A element = relu(sum of 4 split-K partials + Abias[k]).
template<int TRANS_B, int A_DYN, int B_DYN, int A_CMB>
__global__ __launch_bounds__(256) void gemm64(
    const void* __restrict__ A, const void* __restrict__ B,
    const void* __restrict__ Abias, float* __restrict__ C,
    int M, int N, int K, int kLen, size_t aPart, const int* __restrict__ flag)
{
  const bool f32 = (*flag != 0);
  const bool aF = A_DYN ? f32 : true;
  const bool bF = B_DYN ? f32 : true;
  __shared__ float As[16][68];
  __shared__ float Bs[16][68];
  const int tid = threadIdx.x;
  const int m0 = blockIdx.x * 64, n0 = blockIdx.y * 64;
  const int kBeg = blockIdx.z * kLen;
  const int tm = (tid & 15) * 4, tn = (tid >> 4) * 4;
  const int ar = tid >> 2;
  const int ac = (tid & 3) * 4;
  const int br = tid >> 4;
  const int bc = (tid & 15) * 4;
  float acc[4][4] = {};

  for (int kc = kBeg; kc < kBeg + kLen; kc += 16){
    size_t aidx = (size_t)(m0 + ar) * K + kc + ac;
    float4 a4;
    if (A_CMB){
      const float* Af = (const float*)A;
      float4 s0 = ld4f(Af + aidx);
      float4 s1 = ld4f(Af + aPart + aidx);
      float4 s2 = ld4f(Af + 2 * aPart + aidx);
      float4 s3 = ld4f(Af + 3 * aPart + aidx);
      float bx0 = dynld(Abias, kc + ac + 0, f32);
      float bx1 = dynld(Abias, kc + ac + 1, f32);
      float bx2 = dynld(Abias, kc + ac + 2, f32);
      float bx3 = dynld(Abias, kc + ac + 3, f32);
      a4.x = fmaxf(s0.x + s1.x + s2.x + s3.x + bx0, 0.0f);
      a4.y = fmaxf(s0.y + s1.y + s2.y + s3.y + bx1, 0.0f);
      a4.z = fmaxf(s0.z + s1.z + s2.z + s3.z + bx2, 0.0f);
      a4.w = fmaxf(s0.w + s1.w + s2.w + s3.w + bx3, 0.0f);
    } else {
      a4 = aF ? ld4f((const float*)A + aidx) : ld4h((const ushort_t*)A + aidx);
    }
    As[ac+0][ar] = a4.x; As[ac+1][ar] = a4.y; As[ac+2][ar] = a4.z; As[ac+3][ar] = a4.w;
    if (!TRANS_B){
      size_t bidx = (size_t)(kc + br) * N + n0 + bc;
      float4 b4 = bF ? ld4f((const float*)B + bidx) : ld4h((const ushort_t*)B + bidx);
      Bs[br][bc+0] = b4.x; Bs[br][bc+1] = b4.y; Bs[br][bc+2] = b4.z; Bs[br][bc+3] = b4.w;
    } else {
      size_t bidx = (size_t)(n0 + ar) * K + kc + ac;
      float4 b4 = bF ? ld4f((const float*)B + bidx) : ld4h((const ushort_t*)B + bidx);
      Bs[ac+0][ar] = b4.x; Bs[ac+1][ar] = b4.y; Bs[ac+2][ar] = b4.z; Bs[ac+3][ar] = b4.w;
    }
    __syncthreads();
    #pragma unroll
    for (int k = 0; k < 16; k++){
      float av[4], bv[4];
      #pragma unroll
      for (int i = 0; i < 4; i++) av[i] = As[k][tm + i];
      #pragma unroll
      for (int j = 0; j < 4; j++) bv[j] = Bs[k][tn + j];
      #pragma unroll
      for (int i = 0; i < 4; i++)
        #pragma unroll
        for (int j = 0; j < 4; j++) acc[i][j] += av[i] * bv[j];
    }
    __syncthreads();
  }
  #pragma unroll
  for (int i = 0; i < 4; i++)
    #pragma unroll
    for (int j = 0; j < 4; j++)
      C[((size_t)blockIdx.z * M + m0 + tm + i) * N + n0 + tn + j] = acc[i][j];
}

// sum 4 split-K partials (used once, for Wqk preamble)
__global__ __launch_bounds__(256) void combine4(
    const float* __restrict__ in, float* __restrict__ out, int sz)
{
  int i = blockIdx.x * 256 + threadIdx.x;
  out[i] = in[i] + in[sz + i] + in[2 * sz + i] + in[3 * sz + i];
}

// fused gi/gh GEMM: z in [0,8): z&3 = k-split, z>=4 selects gh (A=s_n, B=w_hh^T)
// else gi (A=Ud, B=Wvih dense fp32). N=1536, K=512, M=256.
__global__ __launch_bounds__(256) void gemm_gigh(
    const float* __restrict__ Ud, const float* __restrict__ Wvih,
    const float* __restrict__ s_n, const void* __restrict__ w_hh,
    float* __restrict__ gip, float* __restrict__ ghp,
    const int* __restrict__ flag)
{
  const bool f32 = (*flag != 0);
  const bool doGh = blockIdx.z >= 4;
  const int kz = blockIdx.z & 3;
  __shared__ float As[16][68];
  __shared__ float Bs[16][68];
  const int tid = threadIdx.x;
  const int m0 = blockIdx.x * 64, n0 = blockIdx.y * 64;
  const int kBeg = kz * 128;
  const int tm = (tid & 15) * 4, tn = (tid >> 4) * 4;
  const int ar = tid >> 2;
  const int ac = (tid & 3) * 4;
  const int br = tid >> 4;
  const int bc = (tid & 15) * 4;
  const float* A = doGh ? s_n : Ud;
  float acc[4][4] = {};

  for (int kc = kBeg; kc < kBeg + 128; kc += 16){
    float4 a4 = ld4f(A + (size_t)(m0 + ar) * 512 + kc + ac);
    As[ac+0][ar] = a4.x; As[ac+1][ar] = a4.y; As[ac+2][ar] = a4.z; As[ac+3][ar] = a4.w;
    if (!doGh){
      float4 b4 = ld4f(Wvih + (size_t)(kc + br) * 1536 + n0 + bc);
      Bs[br][bc+0] = b4.x; Bs[br][bc+1] = b4.y; Bs[br][bc+2] = b4.z; Bs[br][bc+3] = b4.w;
    } else {
      size_t bidx = (size_t)(n0 + ar) * 512 + kc + ac;
      float4 b4 = f32 ? ld4f((const float*)w_hh + bidx)
                      : ld4h((const ushort_t*)w_hh + bidx);
      Bs[ac+0][ar] = b4.x; Bs[ac+1][ar] = b4.y; Bs[ac+2][ar] = b4.z; Bs[ac+3][ar] = b4.w;
    }
    __syncthreads();
    #pragma unroll
    for (int k = 0; k < 16; k++){
      float av[4], bv[4];
      #pragma unroll
      for (int i = 0; i < 4; i++) av[i] = As[k][tm + i];
      #pragma unroll
      for (int j = 0; j < 4; j++) bv[j] = Bs[k][tn + j];
      #pragma unroll
      for (int i = 0; i < 4; i++)
        #pragma unroll
        for (int j = 0; j < 4; j++) acc[i][j] += av[i] * bv[j];
    }
    __syncthreads();
  }
  float* C = (doGh ? ghp : gip) + (size_t)kz * 256 * 1536;
  #pragma unroll
  for (int i = 0; i < 4; i++)
    #pragma unroll
    for (int j = 0; j < 4; j++)
      C[(size_t)(m0 + tm + i) * 1536 + n0 + tn + j] = acc[i][j];
}

// merged-dtype big pass; sums the 4 qk split-K partials on register load.
__global__ __launch_bounds__(256, 2) void big_pass(
    const void* __restrict__ features, const float* __restrict__ qkp,
    const void* __restrict__ lnw, const void* __restrict__ lnb,
    void* __restrict__ d_out_base, float* __restrict__ Upart,
    float* __restrict__ Rpart, const int* __restrict__ flag)
{
  const bool F32 = (*flag != 0);
  __shared__ float Ubuf[4][S_ * D_];
  __shared__ float Rbuf[4][S_];
  __shared__ float pbuf[S_][256];
  const int b = blockIdx.y;
  const int tid = threadIdx.x;
  const int wid = tid >> 6, lane = tid & 63;
  const int fblock = blockIdx.x * 256;
  const int f0 = fblock + wid * 64;

  float lw[8], lb[8];
  #pragma unroll
  for (int j = 0; j < 8; j++){
    int d = 8 * lane + j;
    lw[j] = dynld(lnw, d, F32);
    lb[j] = dynld(lnb, d, F32);
  }
  float qkr[8][8];
  #pragma unroll
  for (int s = 0; s < 8; s++){
    const float* qp = qkp + (size_t)(b * S_ + s) * D_ + 8 * lane;
    float4 q0 = ld4f(qp);
    float4 q1 = ld4f(qp + 4);
    #pragma unroll
    for (int p = 1; p < 4; p++){
      const float* qq = qp + (size_t)p * 131072;
      float4 t0 = ld4f(qq), t1 = ld4f(qq + 4);
      q0.x += t0.x; q0.y += t0.y; q0.z += t0.z; q0.w += t0.w;
      q1.x += t1.x; q1.y += t1.y; q1.z += t1.z; q1.w += t1.w;
    }
    qkr[s][0]=q0.x; qkr[s][1]=q0.y; qkr[s][2]=q0.z; qkr[s][3]=q0.w;
    qkr[s][4]=q1.x; qkr[s][5]=q1.y; qkr[s][6]=q1.z; qkr[s][7]=q1.w;
  }
  float U[8][8];
  #pragma unroll
  for (int s = 0; s < 8; s++)
    #pragma unroll
    for (int j = 0; j < 8; j++) U[s][j] = 0.0f;
  float racc[8] = {0,0,0,0,0,0,0,0};

  const size_t base = ((size_t)b * F_ + f0) * D_ + 8 * lane;
  const float* fbf = (const float*)features + base;
  const ushort_t* fbh = (const ushort_t*)features + base;
  float4 nf0 = {}, nf1 = {}; uint4 nh = {};
  if (F32){ nf0 = *(const float4*)fbf; nf1 = *(const float4*)(fbf + 4); }
  else    { nh  = *(const uint4*)fbh; }

  for (int r = 0; r < 64; r++){
    float x[8];
    if (F32){
      float4 c0 = nf0, c1 = nf1;
      if (r < 63){
        nf0 = *(const float4*)(fbf + (size_t)(r + 1) * D_);
        nf1 = *(const float4*)(fbf + (size_t)(r + 1) * D_ + 4);
      }
      x[0]=c0.x; x[1]=c0.y; x[2]=c0.z; x[3]=c0.w;
      x[4]=c1.x; x[5]=c1.y; x[6]=c1.z; x[7]=c1.w;
    } else {
      uint4 cx = nh;
      if (r < 63) nh = *(const uint4*)(fbh + (size_t)(r + 1) * D_);
      x[0]=b2f(cx.x & 0xffff); x[1]=b2f(cx.x >> 16);
      x[2]=b2f(cx.y & 0xffff); x[3]=b2f(cx.y >> 16);
      x[4]=b2f(cx.z & 0xffff); x[5]=b2f(cx.z >> 16);
      x[6]=b2f(cx.w & 0xffff); x[7]=b2f(cx.w >> 16);
    }
    float sum = 0.0f;
    #pragma unroll
    for (int j = 0; j < 8; j++) sum += x[j];
    float mean = allsum64(sum) * (1.0f / 512.0f);
    float var = 0.0f;
    #pragma unroll
    for (int j = 0; j < 8; j++){ x[j] -= mean; var += x[j] * x[j]; }
    var = allsum64(var) * (1.0f / 512.0f);
    float rstd = 1.0f / sqrtf(var + LN_EPS);
    float y[8];
    #pragma unroll
    for (int j = 0; j < 8; j++) y[j] = x[j] * rstd * lw[j] + lb[j];

    float dt[8];
    #pragma unroll
    for (int s = 0; s < 8; s++){
      float t = 0.0f;
      #pragma unroll
      for (int j = 0; j < 8; j++) t += qkr[s][j] * y[j];
      dt[s] = allsum64(t) * SCALE_;
    }
    float mx = dt[0];
    #pragma unroll
    for (int s = 1; s < 8; s++) mx = fmaxf(mx, dt[s]);
    float p[8]; float den = 0.0f;
    #pragma unroll
    for (int s = 0; s < 8; s++){ p[s] = __expf(dt[s] - mx); den += p[s]; }
    float inv = 1.0f / den;
    #pragma unroll
    for (int s = 0; s < 8; s++) p[s] *= inv;
    #pragma unroll
    for (int s = 0; s < 8; s++) if (lane == s) pbuf[s][wid * 64 + r] = p[s];
    #pragma unroll
    for (int s = 0; s < 8; s++){
      float pe = p[s] + EPS_;
      racc[s] += pe;
      #pragma unroll
      for (int j = 0; j < 8; j++) U[s][j] += pe * y[j];
    }
  }
  #pragma unroll
  for (int s = 0; s < 8; s++){
    float* ub = &Ubuf[wid][s * D_ + 8 * lane];
    *(float4*)ub     = make_float4(U[s][0], U[s][1], U[s][2], U[s][3]);
    *(float4*)(ub+4) = make_float4(U[s][4], U[s][5], U[s][6], U[s][7]);
  }
  #pragma unroll
  for (int s = 0; s < 8; s++) if (lane == s) Rbuf[wid][s] = racc[s];
  __syncthreads();
  float* up = Upart + (size_t)(b * 16 + blockIdx.x) * S_ * D_;
  for (int e = tid; e < S_ * D_; e += 256)
    up[e] = Ubuf[0][e] + Ubuf[1][e] + Ubuf[2][e] + Ubuf[3][e];
  if (tid < 8)
    Rpart[(b * 16 + blockIdx.x) * S_ + tid] =
        Rbuf[0][tid] + Rbuf[1][tid] + Rbuf[2][tid] + Rbuf[3][tid];
  #pragma unroll
  for (int s = 0; s < 8; s++){
    size_t oi = 131072 + ((size_t)(b * S_ + s)) * F_ + fblock + tid;
    float pv = pbuf[s][tid];
    if (F32) ((float*)d_out_base)[oi] = pv;
    else     ((bf16*)d_out_base)[oi] = __float2bfloat16(pv);
  }
}

__global__ __launch_bounds__(256) void reduce_updates(
    const float* __restrict__ Upart, const float* __restrict__ Rpart,
    float* __restrict__ Ud)
{
  __shared__ float rinv;
  int bs = blockIdx.x;
  int b = bs >> 3, s = bs & 7;
  int t = threadIdx.x;
  if (t == 0){
    float r = 0.0f;
    for (int w = 0; w < 16; w++) r += Rpart[(b * 16 + w) * S_ + s];
    rinv = 1.0f / r;
  }
  __syncthreads();
  const float* up = Upart + ((size_t)(b * 16) * S_ + s) * D_;
  float ri = rinv;
  #pragma unroll
  for (int u = 0; u < 2; u++){
    int e = t + u * 256;
    float acc = 0.0f;
    for (int w = 0; w < 16; w++) acc += up[(size_t)w * S_ * D_ + e];
    Ud[((size_t)(b * S_ + s)) * D_ + e] = acc * ri;
  }
}

__global__ __launch_bounds__(256) void ln_rows(
    const float* __restrict__ x, const void* __restrict__ w,
    const void* __restrict__ b, float* __restrict__ y, const int* __restrict__ flag)
{
  const bool f32 = (*flag != 0);
  __shared__ float sh[4];
  int row = blockIdx.x, t = threadIdx.x;
  const float* xr = x + (size_t)row * D_;
  float v0 = xr[t], v1 = xr[t + 256];
  float mean = blockSum256(v0 + v1, sh) * (1.0f / 512.0f);
  float d0 = v0 - mean, d1 = v1 - mean;
  float var = blockSum256(d0 * d0 + d1 * d1, sh) * (1.0f / 512.0f);
  float rstd = 1.0f / sqrtf(var + LN_EPS);
  float w0 = dynld(w, t, f32),       w1 = dynld(w, t + 256, f32);
  float b0 = dynld(b, t, f32),       b1 = dynld(b, t + 256, f32);
  y[(size_t)row * D_ + t]       = d0 * rstd * w0 + b0;
  y[(size_t)row * D_ + t + 256] = d1 * rstd * w1 + b1;
}

// fused: sum gi/gh split-K partials + biases -> GRU gates -> snew, then LN(snew)
__global__ __launch_bounds__(256) void gru_combine(
    const float* __restrict__ gip, const float* __restrict__ ghp,
    const void* __restrict__ b_ih, const void* __restrict__ b_hh,
    const float* __restrict__ sn, const void* __restrict__ lw,
    const void* __restrict__ lb, float* __restrict__ snew,
    float* __restrict__ lnm, const int* __restrict__ flag)
{
  const bool f32 = (*flag != 0);
  __shared__ float sh[4];
  int row = blockIdx.x, t = threadIdx.x;
  const float* snr = sn + (size_t)row * D_;
  float v[2];
  #pragma unroll
  for (int u = 0; u < 2; u++){
    int d = t + u * 256;
    float ir = 0, iz = 0, in_ = 0, hr = 0, hz = 0, hn = 0;
    #pragma unroll
    for (int p = 0; p < 4; p++){
      const float* gp = gip + (size_t)p * 393216 + (size_t)row * 1536;
      const float* hp = ghp + (size_t)p * 393216 + (size_t)row * 1536;
      ir  += gp[d]; iz += gp[512 + d]; in_ += gp[1024 + d];
      hr  += hp[d]; hz += hp[512 + d]; hn  += hp[1024 + d];
    }
    ir  += dynld(b_ih, d, f32);
    iz  += dynld(b_ih, 512 + d, f32);
    in_ += dynld(b_ih, 1024 + d, f32);
    hr  += dynld(b_hh, d, f32);
    hz  += dynld(b_hh, 512 + d, f32);
    hn  += dynld(b_hh, 1024 + d, f32);
    float rg = 1.0f / (1.0f + __expf(-(ir + hr)));
    float zg = 1.0f / (1.0f + __expf(-(iz + hz)));
    float a  = in_ + rg * hn;
    float e2 = __expf(2.0f * a);
    float ng = 1.0f - 2.0f / (e2 + 1.0f);
    float h  = snr[d];
    v[u] = (1.0f - zg) * ng + zg * h;
    snew[(size_t)row * D_ + d] = v[u];
  }
  float mean = blockSum256(v[0] + v[1], sh) * (1.0f / 512.0f);
  float d0 = v[0] - mean, d1 = v[1] - mean;
  float var = blockSum256(d0 * d0 + d1 * d1, sh) * (1.0f / 512.0f);
  float rstd = 1.0f / sqrtf(var + LN_EPS);
  float w0 = dynld(lw, t, f32),       w1 = dynld(lw, t + 256, f32);
  float b0 = dynld(lb, t, f32),       b1 = dynld(lb, t + 256, f32);
  lnm[(size_t)row * D_ + t]       = d0 * rstd * w0 + b0;
  lnm[(size_t)row * D_ + t + 256] = d1 * rstd * w1 + b1;
}

template<int FINAL>
__global__ __launch_bounds__(256) void combine_h2(
    const float* __restrict__ snew, const float* __restrict__ h2p,
    const void* __restrict__ b2, float* __restrict__ slots,
    void* __restrict__ out, const int* __restrict__ flag)
{
  const bool f32 = (*flag != 0);
  int idx = blockIdx.x * 256 + threadIdx.x;
  int d = idx & 511;
  float bias = dynld(b2, d, f32);
  float v = snew[idx] + h2p[idx] + h2p[131072 + idx] + h2p[262144 + idx]
          + h2p[393216 + idx] + bias;
  slots[idx] = v;
  if (FINAL){
    if (f32) ((float*)out)[idx] = v;
    else     ((bf16*)out)[idx] = __float2bfloat16(v);
  }
}

__global__ __launch_bounds__(256) void cast_in(const void* __restrict__ in,
                                               float* __restrict__ out,
                                               const int* __restrict__ flag){
  const bool f32 = (*flag != 0);
  int i = blockIdx.x * 256 + threadIdx.x;
  out[i] = f32 ? ((const float*)in)[i] : b2f(((const ushort_t*)in)[i]);
}

extern "C" void kernel_launch(void* const* d_in, const int* in_sizes, int n_in,
                              void* d_out, int out_size, void* d_ws, size_t ws_size,
                              hipStream_t stream)
{
  const void* in_slots  = d_in[0];
  const void* features  = d_in[1];
  const void* w_k   = d_in[2];
  const void* w_v   = d_in[3];
  const void* w_q   = d_in[4];
  const void* ln_feat_w = d_in[5];
  const void* ln_feat_b = d_in[6];
  const void* ln_slot_w = d_in[7];
  const void* ln_slot_b = d_in[8];
  const void* w_ih  = d_in[9];
  const void* w_hh  = d_in[10];
  const void* b_ih  = d_in[11];
  const void* b_hh  = d_in[12];
  const void* ln_mlp_w = d_in[13];
  const void* ln_mlp_b = d_in[14];
  const void* mlp_w1 = d_in[15];
  const void* mlp_b1 = d_in[16];
  const void* mlp_w2 = d_in[17];
  const void* mlp_b2 = d_in[18];

  float* W     = (float*)d_ws;
  int*   flag  = (int*)d_ws;           // first 64 floats reserved
  float* Wqk   = W + 64;               // 262144
  float* slots = Wqk   + 262144;       // 131072
  float* s_n   = slots + 131072;       // 131072
  float* qkp   = s_n   + 131072;       // 4 x 131072
  float* Ud    = qkp   + 524288;       // 131072
  float* Rpart = Ud    + 131072;       // 4096
  float* Upart = Rpart + 4096;         // 2097152
  float* gip   = Upart + 2097152;      // 4 x 393216
  float* ghp   = gip   + 1572864;      // 4 x 393216
  float* lnm   = ghp   + 1572864;      // 131072
  float* snew  = lnm   + 131072;       // 131072
  float* h1p   = snew  + 131072;       // 4 x 524288
  float* h2p   = h1p   + 2097152;      // 4 x 131072
  float* Wqkp  = h2p   + 524288;       // 1048576 (preamble only)
  float* Wvih  = Wqkp  + 1048576;      // 786432  -> total ~44.6 MB

  detect_dtype<<<1, 256, 0, stream>>>((const uint32_t*)features, flag);
  cast_in<<<512, 256, 0, stream>>>(in_slots, slots, flag);
  // Wqk = w_q @ w_k^T (split-K 4 + combine)
  gemm64<1, 1, 1, 0><<<dim3(8, 8, 4), 256, 0, stream>>>(
      w_q, w_k, nullptr, Wqkp, 512, 512, 512, 128, 0, flag);
  combine4<<<1024, 256, 0, stream>>>(Wqkp, Wqk, 262144);
  // Wvih = w_v @ w_ih^T  (folds the per-iter upd GEMM out of the loop)
  gemm64<1, 1, 1, 0><<<dim3(8, 24, 1), 256, 0, stream>>>(
      w_v, w_ih, nullptr, Wvih, 512, 1536, 512, 512, 0, flag);

  for (int it = 0; it < 3; ++it){
    ln_rows<<<256, 256, 0, stream>>>(slots, ln_slot_w, ln_slot_b, s_n, flag);
    // qk partials = s_n @ Wqk (summed inside big_pass)
    gemm64<0, 0, 0, 0><<<dim3(4, 8, 4), 256, 0, stream>>>(
        s_n, Wqk, nullptr, qkp, 256, 512, 512, 128, 0, flag);
    big_pass<<<dim3(16, 32), 256, 0, stream>>>(
        features, qkp, ln_feat_w, ln_feat_b, d_out, Upart, Rpart, flag);
    reduce_updates<<<256, 256, 0, stream>>>(Upart, Rpart, Ud);
    // gi = Ud @ Wvih, gh = s_n @ w_hh^T, fused in one launch (split-K 4 each)
    gemm_gigh<<<dim3(4, 24, 8), 256, 0, stream>>>(
        Ud, Wvih, s_n, w_hh, gip, ghp, flag);
    gru_combine<<<256, 256, 0, stream>>>(gip, ghp, b_ih, b_hh, s_n,
                                         ln_mlp_w, ln_mlp_b, snew, lnm, flag);
    // h1 partials = lnm @ mlp_w1 (bias+relu folded into h2's A-load)
    gemm64<0, 0, 1, 0><<<dim3(4, 32, 4), 256, 0, stream>>>(
        lnm, mlp_w1, nullptr, h1p, 256, 2048, 512, 128, 0, flag);
    // h2 partials = relu(sum(h1p)+b1) @ mlp_w2
    gemm64<0, 0, 1, 1><<<dim3(4, 8, 4), 256, 0, stream>>>(
        h1p, mlp_w2, mlp_b1, h2p, 256, 512, 2048, 512, 524288, flag);
    if (it < 2)
      combine_h2<0><<<512, 256, 0, stream>>>(snew, h2p, mlp_b2, slots, d_out, flag);
    else
      combine_h2<1><<<512, 256, 0, stream>>>(snew, h2p, mlp_b2, slots, d_out, flag);
  }
}

// Round 3
// 1051.769 us; speedup vs baseline: 1.1283x; 1.1283x over previous
//
#include <hip/hip_runtime.h>
#include <hip/hip_bf16.h>
#include <stdint.h>

typedef __hip_bfloat16 bf16;
typedef unsigned short ushort_t;

#define B_ 32
#define F_ 4096
#define S_ 8
#define D_ 512
#define H_ 2048
#define LN_EPS 1e-5f
#define EPS_ 1e-8f
#define SCALE_ 0.044194173824159216f  // 512^-0.5

__device__ __forceinline__ float b2f(ushort_t u){
  union { uint32_t i; float f; } c; c.i = ((uint32_t)u) << 16; return c.f;
}
__device__ __forceinline__ float4 ld4f(const float* p){ return *(const float4*)p; }
__device__ __forceinline__ float4 ld4h(const ushort_t* p){
  ushort4 u = *(const ushort4*)p;
  return make_float4(b2f(u.x), b2f(u.y), b2f(u.z), b2f(u.w));
}
__device__ __forceinline__ float allsum64(float v){
  #pragma unroll
  for (int o = 1; o < 64; o <<= 1) v += __shfl_xor(v, o, 64);
  return v;
}
__device__ __forceinline__ float blockSum256(float v, float* sh){
  v = allsum64(v);
  int wid = threadIdx.x >> 6, lane = threadIdx.x & 63;
  __syncthreads();
  if (lane == 0) sh[wid] = v;
  __syncthreads();
  return sh[0] + sh[1] + sh[2] + sh[3];
}
__device__ __forceinline__ float dynld(const void* p, int i, bool f32){
  return f32 ? ((const float*)p)[i] : b2f(((const ushort_t*)p)[i]);
}

// flag=1 -> tensors are fp32; flag=0 -> bf16 (heuristic on bit patterns).
__global__ void detect_dtype(const uint32_t* __restrict__ w, int* __restrict__ flag){
  __shared__ int sh;
  if (threadIdx.x == 0) sh = 0;
  __syncthreads();
  int c = 0;
  for (int i = threadIdx.x; i < 4096; i += 256){
    uint32_t e = (w[i] >> 7) & 0xFF;
    if (e == 0 || e >= 0xBF) c++;
  }
  atomicAdd(&sh, c);
  __syncthreads();
  if (threadIdx.x == 0) *flag = (sh >= 100) ? 1 : 0;
}

// C = A @ B(^T).  A_CMB: A element = relu(sum of 4 split-K partials + Abias[k]).
template<int TRANS_B, int A_DYN, int B_DYN, int A_CMB>
__global__ __launch_bounds__(256) void gemm64(
    const void* __restrict__ A, const void* __restrict__ B,
    const void* __restrict__ Abias, float* __restrict__ C,
    int M, int N, int K, int kLen, size_t aPart, const int* __restrict__ flag)
{
  const bool f32 = (*flag != 0);
  const bool aF = A_DYN ? f32 : true;
  const bool bF = B_DYN ? f32 : true;
  __shared__ float As[16][68];
  __shared__ float Bs[16][68];
  const int tid = threadIdx.x;
  const int m0 = blockIdx.x * 64, n0 = blockIdx.y * 64;
  const int kBeg = blockIdx.z * kLen;
  const int tm = (tid & 15) * 4, tn = (tid >> 4) * 4;
  const int ar = tid >> 2;
  const int ac = (tid & 3) * 4;
  const int br = tid >> 4;
  const int bc = (tid & 15) * 4;
  float acc[4][4] = {};

  for (int kc = kBeg; kc < kBeg + kLen; kc += 16){
    size_t aidx = (size_t)(m0 + ar) * K + kc + ac;
    float4 a4;
    if (A_CMB){
      const float* Af = (const float*)A;
      float4 s0 = ld4f(Af + aidx);
      float4 s1 = ld4f(Af + aPart + aidx);
      float4 s2 = ld4f(Af + 2 * aPart + aidx);
      float4 s3 = ld4f(Af + 3 * aPart + aidx);
      float bx0 = dynld(Abias, kc + ac + 0, f32);
      float bx1 = dynld(Abias, kc + ac + 1, f32);
      float bx2 = dynld(Abias, kc + ac + 2, f32);
      float bx3 = dynld(Abias, kc + ac + 3, f32);
      a4.x = fmaxf(s0.x + s1.x + s2.x + s3.x + bx0, 0.0f);
      a4.y = fmaxf(s0.y + s1.y + s2.y + s3.y + bx1, 0.0f);
      a4.z = fmaxf(s0.z + s1.z + s2.z + s3.z + bx2, 0.0f);
      a4.w = fmaxf(s0.w + s1.w + s2.w + s3.w + bx3, 0.0f);
    } else {
      a4 = aF ? ld4f((const float*)A + aidx) : ld4h((const ushort_t*)A + aidx);
    }
    As[ac+0][ar] = a4.x; As[ac+1][ar] = a4.y; As[ac+2][ar] = a4.z; As[ac+3][ar] = a4.w;
    if (!TRANS_B){
      size_t bidx = (size_t)(kc + br) * N + n0 + bc;
      float4 b4 = bF ? ld4f((const float*)B + bidx) : ld4h((const ushort_t*)B + bidx);
      Bs[br][bc+0] = b4.x; Bs[br][bc+1] = b4.y; Bs[br][bc+2] = b4.z; Bs[br][bc+3] = b4.w;
    } else {
      size_t bidx = (size_t)(n0 + ar) * K + kc + ac;
      float4 b4 = bF ? ld4f((const float*)B + bidx) : ld4h((const ushort_t*)B + bidx);
      Bs[ac+0][ar] = b4.x; Bs[ac+1][ar] = b4.y; Bs[ac+2][ar] = b4.z; Bs[ac+3][ar] = b4.w;
    }
    __syncthreads();
    #pragma unroll
    for (int k = 0; k < 16; k++){
      float av[4], bv[4];
      #pragma unroll
      for (int i = 0; i < 4; i++) av[i] = As[k][tm + i];
      #pragma unroll
      for (int j = 0; j < 4; j++) bv[j] = Bs[k][tn + j];
      #pragma unroll
      for (int i = 0; i < 4; i++)
        #pragma unroll
        for (int j = 0; j < 4; j++) acc[i][j] += av[i] * bv[j];
    }
    __syncthreads();
  }
  #pragma unroll
  for (int i = 0; i < 4; i++)
    #pragma unroll
    for (int j = 0; j < 4; j++)
      C[((size_t)blockIdx.z * M + m0 + tm + i) * N + n0 + tn + j] = acc[i][j];
}

// sum 4 split-K partials (used once, for Wqk preamble)
__global__ __launch_bounds__(256) void combine4(
    const float* __restrict__ in, float* __restrict__ out, int sz)
{
  int i = blockIdx.x * 256 + threadIdx.x;
  out[i] = in[i] + in[sz + i] + in[2 * sz + i] + in[3 * sz + i];
}

// fused gi/gh GEMM: z in [0,8): z&3 = k-split, z>=4 selects gh (A=s_n, B=w_hh^T)
// else gi (A=Ud, B=Wvih dense fp32). N=1536, K=512, M=256.
__global__ __launch_bounds__(256) void gemm_gigh(
    const float* __restrict__ Ud, const float* __restrict__ Wvih,
    const float* __restrict__ s_n, const void* __restrict__ w_hh,
    float* __restrict__ gip, float* __restrict__ ghp,
    const int* __restrict__ flag)
{
  const bool f32 = (*flag != 0);
  const bool doGh = blockIdx.z >= 4;
  const int kz = blockIdx.z & 3;
  __shared__ float As[16][68];
  __shared__ float Bs[16][68];
  const int tid = threadIdx.x;
  const int m0 = blockIdx.x * 64, n0 = blockIdx.y * 64;
  const int kBeg = kz * 128;
  const int tm = (tid & 15) * 4, tn = (tid >> 4) * 4;
  const int ar = tid >> 2;
  const int ac = (tid & 3) * 4;
  const int br = tid >> 4;
  const int bc = (tid & 15) * 4;
  const float* A = doGh ? s_n : Ud;
  float acc[4][4] = {};

  for (int kc = kBeg; kc < kBeg + 128; kc += 16){
    float4 a4 = ld4f(A + (size_t)(m0 + ar) * 512 + kc + ac);
    As[ac+0][ar] = a4.x; As[ac+1][ar] = a4.y; As[ac+2][ar] = a4.z; As[ac+3][ar] = a4.w;
    if (!doGh){
      float4 b4 = ld4f(Wvih + (size_t)(kc + br) * 1536 + n0 + bc);
      Bs[br][bc+0] = b4.x; Bs[br][bc+1] = b4.y; Bs[br][bc+2] = b4.z; Bs[br][bc+3] = b4.w;
    } else {
      size_t bidx = (size_t)(n0 + ar) * 512 + kc + ac;
      float4 b4 = f32 ? ld4f((const float*)w_hh + bidx)
                      : ld4h((const ushort_t*)w_hh + bidx);
      Bs[ac+0][ar] = b4.x; Bs[ac+1][ar] = b4.y; Bs[ac+2][ar] = b4.z; Bs[ac+3][ar] = b4.w;
    }
    __syncthreads();
    #pragma unroll
    for (int k = 0; k < 16; k++){
      float av[4], bv[4];
      #pragma unroll
      for (int i = 0; i < 4; i++) av[i] = As[k][tm + i];
      #pragma unroll
      for (int j = 0; j < 4; j++) bv[j] = Bs[k][tn + j];
      #pragma unroll
      for (int i = 0; i < 4; i++)
        #pragma unroll
        for (int j = 0; j < 4; j++) acc[i][j] += av[i] * bv[j];
    }
    __syncthreads();
  }
  float* C = (doGh ? ghp : gip) + (size_t)kz * 256 * 1536;
  #pragma unroll
  for (int i = 0; i < 4; i++)
    #pragma unroll
    for (int j = 0; j < 4; j++)
      C[(size_t)(m0 + tm + i) * 1536 + n0 + tn + j] = acc[i][j];
}

// ---- big_pass row loop, dtype specialized at compile time ----
template<int F32>
__device__ __forceinline__ void bp_rows(
    const void* __restrict__ features, size_t base,
    const float (&lw)[8], const float (&lb)[8], const float (&qkr)[8][8],
    float (&U)[8][8], float (&racc)[8], float (*pbuf)[128], int wid, int lane)
{
  const float* fbf = (const float*)features + base;
  const ushort_t* fbh = (const ushort_t*)features + base;
  float4 nf0 = {}, nf1 = {}; uint4 nh = {};
  if (F32){ nf0 = *(const float4*)fbf; nf1 = *(const float4*)(fbf + 4); }
  else    { nh  = *(const uint4*)fbh; }

  for (int r = 0; r < 32; r++){
    float x[8];
    if (F32){
      float4 c0 = nf0, c1 = nf1;
      if (r < 31){
        nf0 = *(const float4*)(fbf + (size_t)(r + 1) * D_);
        nf1 = *(const float4*)(fbf + (size_t)(r + 1) * D_ + 4);
      }
      x[0]=c0.x; x[1]=c0.y; x[2]=c0.z; x[3]=c0.w;
      x[4]=c1.x; x[5]=c1.y; x[6]=c1.z; x[7]=c1.w;
    } else {
      uint4 cx = nh;
      if (r < 31) nh = *(const uint4*)(fbh + (size_t)(r + 1) * D_);
      x[0]=b2f(cx.x & 0xffff); x[1]=b2f(cx.x >> 16);
      x[2]=b2f(cx.y & 0xffff); x[3]=b2f(cx.y >> 16);
      x[4]=b2f(cx.z & 0xffff); x[5]=b2f(cx.z >> 16);
      x[6]=b2f(cx.w & 0xffff); x[7]=b2f(cx.w >> 16);
    }
    float sum = 0.0f;
    #pragma unroll
    for (int j = 0; j < 8; j++) sum += x[j];
    float mean = allsum64(sum) * (1.0f / 512.0f);
    float var = 0.0f;
    #pragma unroll
    for (int j = 0; j < 8; j++){ x[j] -= mean; var += x[j] * x[j]; }
    var = allsum64(var) * (1.0f / 512.0f);
    float rstd = 1.0f / sqrtf(var + LN_EPS);
    float y[8];
    #pragma unroll
    for (int j = 0; j < 8; j++) y[j] = x[j] * rstd * lw[j] + lb[j];

    float dt[8];
    #pragma unroll
    for (int s = 0; s < 8; s++){
      float t = 0.0f;
      #pragma unroll
      for (int j = 0; j < 8; j++) t += qkr[s][j] * y[j];
      dt[s] = allsum64(t) * SCALE_;
    }
    float mx = dt[0];
    #pragma unroll
    for (int s = 1; s < 8; s++) mx = fmaxf(mx, dt[s]);
    float p[8]; float den = 0.0f;
    #pragma unroll
    for (int s = 0; s < 8; s++){ p[s] = __expf(dt[s] - mx); den += p[s]; }
    float inv = 1.0f / den;
    #pragma unroll
    for (int s = 0; s < 8; s++) p[s] *= inv;
    #pragma unroll
    for (int s = 0; s < 8; s++) if (lane == s) pbuf[s][wid * 32 + r] = p[s];
    #pragma unroll
    for (int s = 0; s < 8; s++){
      float pe = p[s] + EPS_;
      racc[s] += pe;
      #pragma unroll
      for (int j = 0; j < 8; j++) U[s][j] += pe * y[j];
    }
  }
}

// grid (32,32): block = 128 feature rows (4 waves x 32). One U/R partial per
// block written straight to global; U staged through a 16KB LDS buffer in 4
// chunked rounds (2 slots each) to keep LDS ~21KB -> 4 blocks/CU.
__global__ __launch_bounds__(256, 2) void big_pass(
    const void* __restrict__ features, const float* __restrict__ qkp,
    const void* __restrict__ lnw, const void* __restrict__ lnb,
    void* __restrict__ d_out_base, float* __restrict__ Upart,
    float* __restrict__ Rpart, const int* __restrict__ flag)
{
  const bool f32rt = (*flag != 0);
  __shared__ float Ubuf[4][2 * D_];   // 16 KB
  __shared__ float pbuf[S_][128];     // 4 KB
  __shared__ float Rbuf[4][S_];
  const int b = blockIdx.y;
  const int tid = threadIdx.x;
  const int wid = tid >> 6, lane = tid & 63;
  const int fblock = blockIdx.x * 128;
  const int f0 = fblock + wid * 32;

  float lw[8], lb[8];
  #pragma unroll
  for (int j = 0; j < 8; j++){
    int d = 8 * lane + j;
    lw[j] = dynld(lnw, d, f32rt);
    lb[j] = dynld(lnb, d, f32rt);
  }
  float qkr[8][8];
  #pragma unroll
  for (int s = 0; s < 8; s++){
    const float* qp = qkp + (size_t)(b * S_ + s) * D_ + 8 * lane;
    float4 q0 = ld4f(qp);
    float4 q1 = ld4f(qp + 4);
    #pragma unroll
    for (int p = 1; p < 4; p++){
      const float* qq = qp + (size_t)p * 131072;
      float4 t0 = ld4f(qq), t1 = ld4f(qq + 4);
      q0.x += t0.x; q0.y += t0.y; q0.z += t0.z; q0.w += t0.w;
      q1.x += t1.x; q1.y += t1.y; q1.z += t1.z; q1.w += t1.w;
    }
    qkr[s][0]=q0.x; qkr[s][1]=q0.y; qkr[s][2]=q0.z; qkr[s][3]=q0.w;
    qkr[s][4]=q1.x; qkr[s][5]=q1.y; qkr[s][6]=q1.z; qkr[s][7]=q1.w;
  }
  float U[8][8] = {};
  float racc[8] = {0,0,0,0,0,0,0,0};
  const size_t base = ((size_t)b * F_ + f0) * D_ + 8 * lane;

  if (f32rt) bp_rows<1>(features, base, lw, lb, qkr, U, racc, pbuf, wid, lane);
  else       bp_rows<0>(features, base, lw, lb, qkr, U, racc, pbuf, wid, lane);

  #pragma unroll
  for (int s = 0; s < 8; s++) if (lane == s) Rbuf[wid][s] = racc[s];
  __syncthreads();   // pbuf + Rbuf ready
  // attention-prob store (1024 elems: s = e>>7, col = e&127)
  #pragma unroll
  for (int e2 = 0; e2 < 4; e2++){
    int e = tid + e2 * 256;
    int s = e >> 7, c = e & 127;
    size_t oi = 131072 + ((size_t)(b * S_ + s)) * F_ + fblock + c;
    float pv = pbuf[s][c];
    if (f32rt) ((float*)d_out_base)[oi] = pv;
    else       ((bf16*)d_out_base)[oi] = __float2bfloat16(pv);
  }
  if (tid < 8)
    Rpart[((size_t)b * 32 + blockIdx.x) * 8 + tid] =
        Rbuf[0][tid] + Rbuf[1][tid] + Rbuf[2][tid] + Rbuf[3][tid];
  // U reduction across the 4 waves, staged 2 slots at a time
  float* up = Upart + ((size_t)b * 32 + blockIdx.x) * (S_ * D_);
  #pragma unroll
  for (int g = 0; g < 4; g++){
    #pragma unroll
    for (int h = 0; h < 2; h++){
      float* ub = &Ubuf[wid][h * D_ + 8 * lane];
      *(float4*)ub     = make_float4(U[2*g+h][0], U[2*g+h][1], U[2*g+h][2], U[2*g+h][3]);
      *(float4*)(ub+4) = make_float4(U[2*g+h][4], U[2*g+h][5], U[2*g+h][6], U[2*g+h][7]);
    }
    __syncthreads();
    for (int e = tid; e < 2 * D_; e += 256)
      up[g * 2 * D_ + e] = Ubuf[0][e] + Ubuf[1][e] + Ubuf[2][e] + Ubuf[3][e];
    if (g < 3) __syncthreads();
  }
}

__global__ __launch_bounds__(256) void reduce_updates(
    const float* __restrict__ Upart, const float* __restrict__ Rpart,
    float* __restrict__ Ud)
{
  __shared__ float rinv;
  int bs = blockIdx.x;
  int b = bs >> 3, s = bs & 7;
  int t = threadIdx.x;
  if (t == 0){
    float r = 0.0f;
    for (int w = 0; w < 32; w++) r += Rpart[((size_t)(b * 32 + w)) * 8 + s];
    rinv = 1.0f / r;
  }
  __syncthreads();
  const float* up = Upart + ((size_t)b * 32 * 8 + s) * 512;
  float ri = rinv;
  #pragma unroll
  for (int u = 0; u < 2; u++){
    int e = t + u * 256;
    float acc = 0.0f;
    for (int w = 0; w < 32; w++) acc += up[(size_t)w * 4096 + e];
    Ud[((size_t)(b * S_ + s)) * D_ + e] = acc * ri;
  }
}

__global__ __launch_bounds__(256) void ln_rows(
    const float* __restrict__ x, const void* __restrict__ w,
    const void* __restrict__ b, float* __restrict__ y, const int* __restrict__ flag)
{
  const bool f32 = (*flag != 0);
  __shared__ float sh[4];
  int row = blockIdx.x, t = threadIdx.x;
  const float* xr = x + (size_t)row * D_;
  float v0 = xr[t], v1 = xr[t + 256];
  float mean = blockSum256(v0 + v1, sh) * (1.0f / 512.0f);
  float d0 = v0 - mean, d1 = v1 - mean;
  float var = blockSum256(d0 * d0 + d1 * d1, sh) * (1.0f / 512.0f);
  float rstd = 1.0f / sqrtf(var + LN_EPS);
  float w0 = dynld(w, t, f32),       w1 = dynld(w, t + 256, f32);
  float b0 = dynld(b, t, f32),       b1 = dynld(b, t + 256, f32);
  y[(size_t)row * D_ + t]       = d0 * rstd * w0 + b0;
  y[(size_t)row * D_ + t + 256] = d1 * rstd * w1 + b1;
}

// fused: sum gi/gh split-K partials + biases -> GRU gates -> snew, then LN(snew)
__global__ __launch_bounds__(256) void gru_combine(
    const float* __restrict__ gip, const float* __restrict__ ghp,
    const void* __restrict__ b_ih, const void* __restrict__ b_hh,
    const float* __restrict__ sn, const void* __restrict__ lw,
    const void* __restrict__ lb, float* __restrict__ snew,
    float* __restrict__ lnm, const int* __restrict__ flag)
{
  const bool f32 = (*flag != 0);
  __shared__ float sh[4];
  int row = blockIdx.x, t = threadIdx.x;
  const float* snr = sn + (size_t)row * D_;
  float v[2];
  #pragma unroll
  for (int u = 0; u < 2; u++){
    int d = t + u * 256;
    float ir = 0, iz = 0, in_ = 0, hr = 0, hz = 0, hn = 0;
    #pragma unroll
    for (int p = 0; p < 4; p++){
      const float* gp = gip + (size_t)p * 393216 + (size_t)row * 1536;
      const float* hp = ghp + (size_t)p * 393216 + (size_t)row * 1536;
      ir  += gp[d]; iz += gp[512 + d]; in_ += gp[1024 + d];
      hr  += hp[d]; hz += hp[512 + d]; hn  += hp[1024 + d];
    }
    ir  += dynld(b_ih, d, f32);
    iz  += dynld(b_ih, 512 + d, f32);
    in_ += dynld(b_ih, 1024 + d, f32);
    hr  += dynld(b_hh, d, f32);
    hz  += dynld(b_hh, 512 + d, f32);
    hn  += dynld(b_hh, 1024 + d, f32);
    float rg = 1.0f / (1.0f + __expf(-(ir + hr)));
    float zg = 1.0f / (1.0f + __expf(-(iz + hz)));
    float a  = in_ + rg * hn;
    float e2 = __expf(2.0f * a);
    float ng = 1.0f - 2.0f / (e2 + 1.0f);
    float h  = snr[d];
    v[u] = (1.0f - zg) * ng + zg * h;
    snew[(size_t)row * D_ + d] = v[u];
  }
  float mean = blockSum256(v[0] + v[1], sh) * (1.0f / 512.0f);
  float d0 = v[0] - mean, d1 = v[1] - mean;
  float var = blockSum256(d0 * d0 + d1 * d1, sh) * (1.0f / 512.0f);
  float rstd = 1.0f / sqrtf(var + LN_EPS);
  float w0 = dynld(lw, t, f32),       w1 = dynld(lw, t + 256, f32);
  float b0 = dynld(lb, t, f32),       b1 = dynld(lb, t + 256, f32);
  lnm[(size_t)row * D_ + t]       = d0 * rstd * w0 + b0;
  lnm[(size_t)row * D_ + t + 256] = d1 * rstd * w1 + b1;
}

// fused: slots_new = snew + sum(8 h2 partials) + b2; then either LN -> s_n
// (next iteration) or dtype-cast store to d_out (final iteration).
template<int FINAL>
__global__ __launch_bounds__(256) void combine_ln(
    const float* __restrict__ snew, const float* __restrict__ h2p,
    const void* __restrict__ b2, const void* __restrict__ lnw,
    const void* __restrict__ lnb, float* __restrict__ s_n,
    void* __restrict__ out, const int* __restrict__ flag)
{
  const bool f32 = (*flag != 0);
  __shared__ float sh[4];
  int row = blockIdx.x, t = threadIdx.x;
  float v[2];
  #pragma unroll
  for (int u = 0; u < 2; u++){
    int d = t + u * 256;
    size_t idx = (size_t)row * D_ + d;
    float acc = snew[idx];
    #pragma unroll
    for (int p = 0; p < 8; p++) acc += h2p[(size_t)p * 131072 + idx];
    acc += dynld(b2, d, f32);
    v[u] = acc;
    if (FINAL){
      if (f32) ((float*)out)[idx] = acc;
      else     ((bf16*)out)[idx] = __float2bfloat16(acc);
    }
  }
  if (!FINAL){
    float mean = blockSum256(v[0] + v[1], sh) * (1.0f / 512.0f);
    float d0 = v[0] - mean, d1 = v[1] - mean;
    float var = blockSum256(d0 * d0 + d1 * d1, sh) * (1.0f / 512.0f);
    float rstd = 1.0f / sqrtf(var + LN_EPS);
    float w0 = dynld(lnw, t, f32),       w1 = dynld(lnw, t + 256, f32);
    float b0 = dynld(lnb, t, f32),       b1 = dynld(lnb, t + 256, f32);
    s_n[(size_t)row * D_ + t]       = d0 * rstd * w0 + b0;
    s_n[(size_t)row * D_ + t + 256] = d1 * rstd * w1 + b1;
  }
}

__global__ __launch_bounds__(256) void cast_in(const void* __restrict__ in,
                                               float* __restrict__ out,
                                               const int* __restrict__ flag){
  const bool f32 = (*flag != 0);
  int i = blockIdx.x * 256 + threadIdx.x;
  out[i] = f32 ? ((const float*)in)[i] : b2f(((const ushort_t*)in)[i]);
}

extern "C" void kernel_launch(void* const* d_in, const int* in_sizes, int n_in,
                              void* d_out, int out_size, void* d_ws, size_t ws_size,
                              hipStream_t stream)
{
  const void* in_slots  = d_in[0];
  const void* features  = d_in[1];
  const void* w_k   = d_in[2];
  const void* w_v   = d_in[3];
  const void* w_q   = d_in[4];
  const void* ln_feat_w = d_in[5];
  const void* ln_feat_b = d_in[6];
  const void* ln_slot_w = d_in[7];
  const void* ln_slot_b = d_in[8];
  const void* w_ih  = d_in[9];
  const void* w_hh  = d_in[10];
  const void* b_ih  = d_in[11];
  const void* b_hh  = d_in[12];
  const void* ln_mlp_w = d_in[13];
  const void* ln_mlp_b = d_in[14];
  const void* mlp_w1 = d_in[15];
  const void* mlp_b1 = d_in[16];
  const void* mlp_w2 = d_in[17];
  const void* mlp_b2 = d_in[18];

  float* W     = (float*)d_ws;
  int*   flag  = (int*)d_ws;           // first 64 floats reserved
  float* Wqk   = W + 64;               // 262144
  float* slots = Wqk   + 262144;       // 131072
  float* s_n   = slots + 131072;       // 131072
  float* qkp   = s_n   + 131072;       // 4 x 131072
  float* Ud    = qkp   + 524288;       // 131072
  float* Rpart = Ud    + 131072;       // 32*32*8 = 8192
  float* Upart = Rpart + 8192;         // 32*32*8*512 = 4194304
  float* gip   = Upart + 4194304;      // 4 x 393216
  float* ghp   = gip   + 1572864;      // 4 x 393216
  float* lnm   = ghp   + 1572864;      // 131072
  float* snew  = lnm   + 131072;       // 131072
  float* h1p   = snew  + 131072;       // 4 x 524288
  float* h2p   = h1p   + 2097152;      // 8 x 131072
  float* Wqkp  = h2p   + 1048576;      // 1048576 (preamble only)
  float* Wvih  = Wqkp  + 1048576;      // 786432  -> total ~54 MB

  detect_dtype<<<1, 256, 0, stream>>>((const uint32_t*)features, flag);
  cast_in<<<512, 256, 0, stream>>>(in_slots, slots, flag);
  // Wqk = w_q @ w_k^T (split-K 4 + combine)
  gemm64<1, 1, 1, 0><<<dim3(8, 8, 4), 256, 0, stream>>>(
      w_q, w_k, nullptr, Wqkp, 512, 512, 512, 128, 0, flag);
  combine4<<<1024, 256, 0, stream>>>(Wqkp, Wqk, 262144);
  // Wvih = w_v @ w_ih^T  (folds the per-iter upd GEMM out of the loop)
  gemm64<1, 1, 1, 0><<<dim3(8, 24, 1), 256, 0, stream>>>(
      w_v, w_ih, nullptr, Wvih, 512, 1536, 512, 512, 0, flag);
  // s_n for iteration 0 (later iterations get it from combine_ln)
  ln_rows<<<256, 256, 0, stream>>>(slots, ln_slot_w, ln_slot_b, s_n, flag);

  for (int it = 0; it < 3; ++it){
    // qk partials = s_n @ Wqk (summed inside big_pass)
    gemm64<0, 0, 0, 0><<<dim3(4, 8, 4), 256, 0, stream>>>(
        s_n, Wqk, nullptr, qkp, 256, 512, 512, 128, 0, flag);
    big_pass<<<dim3(32, 32), 256, 0, stream>>>(
        features, qkp, ln_feat_w, ln_feat_b, d_out, Upart, Rpart, flag);
    reduce_updates<<<256, 256, 0, stream>>>(Upart, Rpart, Ud);
    // gi = Ud @ Wvih, gh = s_n @ w_hh^T, fused in one launch (split-K 4 each)
    gemm_gigh<<<dim3(4, 24, 8), 256, 0, stream>>>(
        Ud, Wvih, s_n, w_hh, gip, ghp, flag);
    gru_combine<<<256, 256, 0, stream>>>(gip, ghp, b_ih, b_hh, s_n,
                                         ln_mlp_w, ln_mlp_b, snew, lnm, flag);
    // h1 partials = lnm @ mlp_w1 (bias+relu folded into h2's A-load)
    gemm64<0, 0, 1, 0><<<dim3(4, 32, 4), 256, 0, stream>>>(
        lnm, mlp_w1, nullptr, h1p, 256, 2048, 512, 128, 0, flag);
    // h2 partials = relu(sum(h1p)+b1) @ mlp_w2, split-K 8
    gemm64<0, 0, 1, 1><<<dim3(4, 8, 8), 256, 0, stream>>>(
        h1p, mlp_w2, mlp_b1, h2p, 256, 512, 2048, 256, 524288, flag);
    if (it < 2)
      combine_ln<0><<<256, 256, 0, stream>>>(snew, h2p, mlp_b2, ln_slot_w,
                                             ln_slot_b, s_n, d_out, flag);
    else
      combine_ln<1><<<256, 256, 0, stream>>>(snew, h2p, mlp_b2, ln_slot_w,
                                             ln_slot_b, s_n, d_out, flag);
  }
}